// Round 3
// baseline (76.779 us; speedup 1.0000x reference)
//
#include <hip/hip_runtime.h>
#include <math.h>

#define DIMQ 16
#define HID  128
#define SPB  32          // samples per block (4 waves x 8 samples/wave)
#define NTHREADS 256
#define SCR_STRIDE 148   // per-sample f32 scratch stride (s[128] phase, then rhs-redist [16][9])

#define DOT4(acc, v, arr, base)                    \
    acc = fmaf((v).x, arr[(base) + 0], acc);       \
    acc = fmaf((v).y, arr[(base) + 1], acc);       \
    acc = fmaf((v).z, arr[(base) + 2], acc);       \
    acc = fmaf((v).w, arr[(base) + 3], acc);

__global__ __launch_bounds__(NTHREADS, 4)
void lag_accel_kernel(const float* __restrict__ y,    // [BATCH][32]
                      const float* __restrict__ W1,   // [128][32]
                      const float* __restrict__ b1,   // [128]
                      const float* __restrict__ w2,   // [128]
                      float* __restrict__ out)        // [BATCH][16]
{
    __shared__ float BTl[16 * 132];              // BTl[j*132+h] = W1[h][16+j]
    __shared__ float scratch[SPB * SCR_STRIDE];  // per-sample: s[128], later rhs partials
    __shared__ float b1s[HID], w2s[HID];

    const int tid = threadIdx.x;

    // stage transposed B, b1, w2
    for (int idx = tid; idx < HID * DIMQ; idx += NTHREADS) {
        int h = idx >> 4, j = idx & 15;
        BTl[j * 132 + h] = W1[h * 32 + 16 + j];
    }
    if (tid < HID) { b1s[tid] = b1[tid]; w2s[tid] = w2[tid]; }

    const int wave = tid >> 6;
    const int lane = tid & 63;
    const int g    = lane >> 3;      // group within wave = sample within wave
    const int l    = lane & 7;       // lane within 8-lane group
    const int smp  = wave * 8 + g;   // sample within block
    const long long s0 = (long long)blockIdx.x * SPB;

    // y sample into registers (VMEM, 8 lanes share same 128B line -> L1 broadcast)
    float q[16], qd[16];
    {
        const float4* y4 = (const float4*)(y + (s0 + smp) * 32);
        float4 t0=y4[0],t1=y4[1],t2=y4[2],t3=y4[3],t4=y4[4],t5=y4[5],t6=y4[6],t7=y4[7];
        q[0]=t0.x;q[1]=t0.y;q[2]=t0.z;q[3]=t0.w;  q[4]=t1.x;q[5]=t1.y;q[6]=t1.z;q[7]=t1.w;
        q[8]=t2.x;q[9]=t2.y;q[10]=t2.z;q[11]=t2.w; q[12]=t3.x;q[13]=t3.y;q[14]=t3.z;q[15]=t3.w;
        qd[0]=t4.x;qd[1]=t4.y;qd[2]=t4.z;qd[3]=t4.w; qd[4]=t5.x;qd[5]=t5.y;qd[6]=t5.z;qd[7]=t5.w;
        qd[8]=t6.x;qd[9]=t6.y;qd[10]=t6.z;qd[11]=t6.w; qd[12]=t7.x;qd[13]=t7.y;qd[14]=t7.z;qd[15]=t7.w;
    }

    __syncthreads();

    float* sscr = &scratch[smp * SCR_STRIDE];   // 16B-aligned (148*4 = 592 = 37*16)

    // ---- phase 1: 16 hidden units per lane (h = 16*l + m); W1 rows from global/L1 ----
    float prhs[16];
#pragma unroll
    for (int i = 0; i < 16; ++i) prhs[i] = 0.0f;

#pragma unroll 1
    for (int m = 0; m < 16; ++m) {
        const int h = (l << 4) + m;
        const float4* wrow = (const float4*)(W1 + h * 32);
        float4 a0 = wrow[0], a1 = wrow[1], a2 = wrow[2], a3 = wrow[3];
        float4 c0 = wrow[4], c1 = wrow[5], c2 = wrow[6], c3 = wrow[7];

        float z = b1s[h];
        float aqd = 0.0f;
        DOT4(z, a0, q, 0)   DOT4(z, a1, q, 4)   DOT4(z, a2, q, 8)   DOT4(z, a3, q, 12)
        DOT4(z, c0, qd, 0)  DOT4(z, c1, qd, 4)  DOT4(z, c2, qd, 8)  DOT4(z, c3, qd, 12)
        DOT4(aqd, a0, qd, 0) DOT4(aqd, a1, qd, 4) DOT4(aqd, a2, qd, 8) DOT4(aqd, a3, qd, 12)

        // branch-free tanh: r = 2/(e^{2z}+1), t = 1-r, sech^2 = r(2-r)
        float e = __expf(2.0f * z);
        float r = 2.0f * __builtin_amdgcn_rcpf(e + 1.0f);
        float t = 1.0f - r;
        float u = w2s[h] * (r * (2.0f - r));
        float s = -2.0f * t * u;
        float sp = s * aqd;

        sscr[h] = s;   // only s needs broadcasting later

        // fused rhs partials: prhs[j] += u*A[h][j] - sp*B[h][j]
#define PRH(j, Av, Bv, c)  prhs[j] = fmaf(u, (Av).c, fmaf(-sp, (Bv).c, prhs[j]));
        PRH(0,a0,c0,x)  PRH(1,a0,c0,y)  PRH(2,a0,c0,z)  PRH(3,a0,c0,w)
        PRH(4,a1,c1,x)  PRH(5,a1,c1,y)  PRH(6,a1,c1,z)  PRH(7,a1,c1,w)
        PRH(8,a2,c2,x)  PRH(9,a2,c2,y)  PRH(10,a2,c2,z) PRH(11,a2,c2,w)
        PRH(12,a3,c3,x) PRH(13,a3,c3,y) PRH(14,a3,c3,z) PRH(15,a3,c3,w)
#undef PRH
    }

    // ---- phase 2: M = I + sum_h s_h B_h B_h^T ; lane owns rows l and l+8 ----
    float M0[16], M1[16];
#pragma unroll
    for (int i = 0; i < 16; ++i) { M0[i] = (i == l) ? 1.0f : 0.0f; M1[i] = (i == l + 8) ? 1.0f : 0.0f; }

    const float* btr0 = &BTl[l * 132];
    const float* btr1 = &BTl[(l + 8) * 132];

#pragma unroll 2
    for (int hc = 0; hc < 32; ++hc) {
        float4 sv  = *(const float4*)&sscr[hc * 4];   // broadcast within group
        float4 bv0 = *(const float4*)&btr0[hc * 4];   // broadcast across groups
        float4 bv1 = *(const float4*)&btr1[hc * 4];
        const float* Wb = W1 + (hc * 4) * 32 + 16;    // wave-uniform -> s_load rows

#define MACC(c, hh)                                                     \
        {                                                               \
            float sB0 = sv.c * bv0.c;                                   \
            float sB1 = sv.c * bv1.c;                                   \
            const float* Br = Wb + (hh) * 32;                           \
            _Pragma("unroll")                                           \
            for (int i = 0; i < 16; ++i) {                              \
                M0[i] = fmaf(sB0, Br[i], M0[i]);                        \
                M1[i] = fmaf(sB1, Br[i], M1[i]);                        \
            }                                                           \
        }
        MACC(x, 0) MACC(y, 1) MACC(z, 2) MACC(w, 3)
#undef MACC
    }

    // ---- redistribute rhs partials (reuses sscr; in-wave ordering, no barrier) ----
#pragma unroll
    for (int jj = 0; jj < 16; ++jj) sscr[jj * 9 + l] = prhs[jj];
    float rhs0 = 0.0f, rhs1 = 0.0f;
#pragma unroll
    for (int p = 0; p < 8; ++p) {
        rhs0 += sscr[l * 9 + p];
        rhs1 += sscr[(l + 8) * 9 + p];
    }

    // ---- solve M x = rhs: Gauss-Jordan over 8-lane groups, 2 rows per lane ----
    float d0 = 1.0f, d1 = 1.0f;
#pragma unroll
    for (int k = 0; k < 16; ++k) {
        float pk[16];
#pragma unroll
        for (int i = k; i < 16; ++i)
            pk[i] = __shfl((k < 8) ? M0[i] : M1[i], k & 7, 8);
        float piv = pk[k];
        float invp = __builtin_amdgcn_rcpf(piv);
        invp = invp * (2.0f - piv * invp);           // 1 NR step
        float f0 = M0[k] * invp;
        float f1 = M1[k] * invp;
        if (k < 8) { f0 = (l == k) ? 0.0f : f0;       d0 = (l == k) ? piv : d0; }
        else       { f1 = (l == (k - 8)) ? 0.0f : f1; d1 = (l == (k - 8)) ? piv : d1; }
#pragma unroll
        for (int i = k; i < 16; ++i) {
            M0[i] = fmaf(-f0, pk[i], M0[i]);
            M1[i] = fmaf(-f1, pk[i], M1[i]);
        }
        float rk = __shfl((k < 8) ? rhs0 : rhs1, k & 7, 8);
        rhs0 = fmaf(-f0, rk, rhs0);
        rhs1 = fmaf(-f1, rk, rhs1);
    }
    float i0 = __builtin_amdgcn_rcpf(d0); i0 = i0 * (2.0f - d0 * i0);
    float i1 = __builtin_amdgcn_rcpf(d1); i1 = i1 * (2.0f - d1 * i1);

    float* ob = out + (s0 + smp) * DIMQ;
    ob[l]     = rhs0 * i0;
    ob[l + 8] = rhs1 * i1;
}

extern "C" void kernel_launch(void* const* d_in, const int* in_sizes, int n_in,
                              void* d_out, int out_size, void* d_ws, size_t ws_size,
                              hipStream_t stream) {
    const float* y  = (const float*)d_in[0];
    const float* W1 = (const float*)d_in[1];
    const float* b1 = (const float*)d_in[2];
    const float* w2 = (const float*)d_in[3];
    float* out = (float*)d_out;
    const int batch = in_sizes[0] / 32;          // 32768
    const int blocks = (batch + SPB - 1) / SPB;  // 1024
    lag_accel_kernel<<<blocks, NTHREADS, 0, stream>>>(y, W1, b1, w2, out);
}

// Round 4
// 72.475 us; speedup vs baseline: 1.0594x; 1.0594x over previous
//
#include <hip/hip_runtime.h>
#include <math.h>

#define DIMQ 16
#define HID  128
#define SPB  32          // samples per block (8 waves x 4 samples/wave)
#define NTHREADS 512
#define SSTR 20          // s-staging stride/sample (80B = 5*16 -> float4-aligned, banks spread)
#define TSTR 324         // transpose scratch stride/sample (1296B = 81*16; smp*4 bank skew)

#define DOT4(acc, v, arr, base)                    \
    acc = fmaf((v).x, arr[(base) + 0], acc);       \
    acc = fmaf((v).y, arr[(base) + 1], acc);       \
    acc = fmaf((v).z, arr[(base) + 2], acc);       \
    acc = fmaf((v).w, arr[(base) + 3], acc);

__global__ __launch_bounds__(NTHREADS, 4)
void lag_accel_kernel(const float* __restrict__ y,    // [BATCH][32]
                      const float* __restrict__ W1,   // [128][32]
                      const float* __restrict__ b1,   // [128]
                      const float* __restrict__ w2,   // [128]
                      float* __restrict__ out)        // [BATCH][16]
{
    __shared__ float BTl[DIMQ * 132];        // BTl[j*132+h] = B[h][j] = W1[h][16+j]
    __shared__ float sstg[SPB * SSTR];       // per-sample s[16] staging (per hb)
    __shared__ float tscr[SPB * TSTR];       // per-sample rhs-partial transpose
    __shared__ float b1s[HID], w2s[HID];

    const int tid = threadIdx.x;

    for (int idx = tid; idx < HID * DIMQ; idx += NTHREADS) {
        int h = idx >> 4, jj = idx & 15;
        BTl[jj * 132 + h] = W1[h * 32 + 16 + jj];
    }
    if (tid < HID) { b1s[tid] = b1[tid]; w2s[tid] = w2[tid]; }

    const int wave = tid >> 6;
    const int lane = tid & 63;
    const int grp  = lane >> 4;
    const int j    = lane & 15;       // lane's row/col index
    const int smp  = wave * 4 + grp;  // sample within block
    const long long s0 = (long long)blockIdx.x * SPB;

    // y sample into registers (VMEM; off the DS pipe)
    float q[16], qd[16];
    {
        const float4* y4 = (const float4*)(y + (s0 + smp) * 32);
        float4 t0=y4[0],t1=y4[1],t2=y4[2],t3=y4[3],t4=y4[4],t5=y4[5],t6=y4[6],t7=y4[7];
        q[0]=t0.x;q[1]=t0.y;q[2]=t0.z;q[3]=t0.w;  q[4]=t1.x;q[5]=t1.y;q[6]=t1.z;q[7]=t1.w;
        q[8]=t2.x;q[9]=t2.y;q[10]=t2.z;q[11]=t2.w; q[12]=t3.x;q[13]=t3.y;q[14]=t3.z;q[15]=t3.w;
        qd[0]=t4.x;qd[1]=t4.y;qd[2]=t4.z;qd[3]=t4.w; qd[4]=t5.x;qd[5]=t5.y;qd[6]=t5.z;qd[7]=t5.w;
        qd[8]=t6.x;qd[9]=t6.y;qd[10]=t6.z;qd[11]=t6.w; qd[12]=t7.x;qd[13]=t7.y;qd[14]=t7.z;qd[15]=t7.w;
    }

    __syncthreads();

    float Mrow[16];
#pragma unroll
    for (int i = 0; i < 16; ++i) Mrow[i] = (i == j) ? 1.0f : 0.0f;
    float prhs[16];
#pragma unroll
    for (int i = 0; i < 16; ++i) prhs[i] = 0.0f;

    float* ss = &sstg[smp * SSTR];

#pragma unroll 1
    for (int hb = 0; hb < HID / 16; ++hb) {
        const int hj = (hb << 4) + j;

        // ---- phase 1: lane's hidden unit hj; W1 row from global (L1-resident).
        // ~780 cyc of dependent compute follows these 8 loads -> latency hidden.
        const float4* wrow = (const float4*)(W1 + hj * 32);
        float4 a0 = wrow[0], a1 = wrow[1], a2 = wrow[2], a3 = wrow[3];
        float4 c0 = wrow[4], c1 = wrow[5], c2 = wrow[6], c3 = wrow[7];

        float z = b1s[hj];
        float aqd = 0.0f;
        DOT4(z, a0, q, 0)   DOT4(z, a1, q, 4)   DOT4(z, a2, q, 8)   DOT4(z, a3, q, 12)
        DOT4(z, c0, qd, 0)  DOT4(z, c1, qd, 4)  DOT4(z, c2, qd, 8)  DOT4(z, c3, qd, 12)
        DOT4(aqd, a0, qd, 0) DOT4(aqd, a1, qd, 4) DOT4(aqd, a2, qd, 8) DOT4(aqd, a3, qd, 12)

        // branch-free tanh: r = 2/(e^{2z}+1), t = 1-r, sech^2 = r(2-r)
        float e = __expf(2.0f * z);
        float r = 2.0f * __builtin_amdgcn_rcpf(e + 1.0f);
        float t = 1.0f - r;
        float u = w2s[hj] * (r * (2.0f - r));
        float s = -2.0f * t * u;
        float sp = s * aqd;

        ss[j] = s;   // only s goes through LDS (same-wave write->read, no barrier)

        // fused rhs partials: prhs[jj] += u*A[hj][jj] - sp*B[hj][jj]
#define PRH(jj, Av, Bv, c)  prhs[jj] = fmaf(u, (Av).c, fmaf(-sp, (Bv).c, prhs[jj]));
        PRH(0,a0,c0,x)  PRH(1,a0,c0,y)  PRH(2,a0,c0,z)  PRH(3,a0,c0,w)
        PRH(4,a1,c1,x)  PRH(5,a1,c1,y)  PRH(6,a1,c1,z)  PRH(7,a1,c1,w)
        PRH(8,a2,c2,x)  PRH(9,a2,c2,y)  PRH(10,a2,c2,z) PRH(11,a2,c2,w)
        PRH(12,a3,c3,x) PRH(13,a3,c3,y) PRH(14,a3,c3,z) PRH(15,a3,c3,w)
#undef PRH

        // ---- phase 2: Mrow[i] += s_h * B[h][j] * B[h][i] over this hb's 16 h's
        const float* base2 = W1 + (hb << 4) * 32 + 16;   // wave-uniform -> s_load
        const float* bt = &BTl[j * 132 + (hb << 4)];
#pragma unroll
        for (int c = 0; c < 4; ++c) {
            float4 sv = *(const float4*)&ss[4 * c];      // group-broadcast
            float4 bv = *(const float4*)&bt[4 * c];      // 2-way bank alias = free
#define MACC(cc, hh)                                                    \
            {                                                           \
                float sB = sv.cc * bv.cc;                               \
                const float* Br = base2 + (4 * c + (hh)) * 32;          \
                _Pragma("unroll")                                       \
                for (int i = 0; i < 16; ++i)                            \
                    Mrow[i] = fmaf(sB, Br[i], Mrow[i]);                 \
            }
            MACC(x, 0) MACC(y, 1) MACC(z, 2) MACC(w, 3)
#undef MACC
        }
    }

    // ---- redistribute rhs partials: transpose within 16-lane group via LDS ----
    float* ts = &tscr[smp * TSTR];
#pragma unroll
    for (int jj = 0; jj < 16; ++jj) ts[jj * 20 + j] = prhs[jj];
    float rhs = 0.0f;
#pragma unroll
    for (int c = 0; c < 4; ++c) {
        float4 v = *(const float4*)&ts[j * 20 + 4 * c];
        rhs += (v.x + v.y) + (v.z + v.w);
    }

    // ---- solve M x = rhs: non-normalizing Gauss-Jordan, triangular skip ----
    float diagj = 1.0f;
#pragma unroll
    for (int k = 0; k < 16; ++k) {
        float piv = __shfl(Mrow[k], k, 16);
        float invp = __builtin_amdgcn_rcpf(piv);
        invp = invp * (2.0f - piv * invp);          // 1 NR step
        float factor = Mrow[k] * invp;
        factor = (j == k) ? 0.0f : factor;
        diagj  = (j == k) ? piv : diagj;
#pragma unroll
        for (int i = k; i < 16; ++i) {
            float mki = __shfl(Mrow[i], k, 16);
            Mrow[i] = fmaf(-factor, mki, Mrow[i]);
        }
        float rk = __shfl(rhs, k, 16);
        rhs = fmaf(-factor, rk, rhs);
    }
    float invd = __builtin_amdgcn_rcpf(diagj);
    invd = invd * (2.0f - diagj * invd);
    out[(s0 + smp) * DIMQ + j] = rhs * invd;
}

extern "C" void kernel_launch(void* const* d_in, const int* in_sizes, int n_in,
                              void* d_out, int out_size, void* d_ws, size_t ws_size,
                              hipStream_t stream) {
    const float* y  = (const float*)d_in[0];
    const float* W1 = (const float*)d_in[1];
    const float* b1 = (const float*)d_in[2];
    const float* w2 = (const float*)d_in[3];
    float* out = (float*)d_out;
    const int batch = in_sizes[0] / 32;          // 32768
    const int blocks = (batch + SPB - 1) / SPB;  // 1024
    lag_accel_kernel<<<blocks, NTHREADS, 0, stream>>>(y, W1, b1, w2, out);
}

// Round 5
// 49.178 us; speedup vs baseline: 1.5612x; 1.4737x over previous
//
#include <hip/hip_runtime.h>
#include <math.h>

#define DIMQ 16
#define HID  128
#define SPB  32          // samples per block (8 waves x 4 samples/wave)
#define NTHREADS 512
#define SSTR 20          // s-staging stride/sample (80B: float4-aligned, groups on disjoint banks)

#define DOT4(acc, v, arr, base)                    \
    acc = fmaf((v).x, arr[(base) + 0], acc);       \
    acc = fmaf((v).y, arr[(base) + 1], acc);       \
    acc = fmaf((v).z, arr[(base) + 2], acc);       \
    acc = fmaf((v).w, arr[(base) + 3], acc);

__global__ __launch_bounds__(NTHREADS, 4)
void lag_accel_kernel(const float* __restrict__ y,    // [BATCH][32]
                      const float* __restrict__ W1,   // [128][32]
                      const float* __restrict__ b1,   // [128]
                      const float* __restrict__ w2,   // [128]
                      float* __restrict__ out)        // [BATCH][16]
{
    __shared__ float W1row[HID][36];     // row-major, 36-pad (16B-aligned, 2-way alias = free)
    __shared__ float BTl[DIMQ * 132];    // BTl[j*132+h] = B[h][j] = W1[h][16+j]
    __shared__ float sstg[SPB * SSTR];   // per-sample s[16] staging (per hb)
    __shared__ float b1s[HID], w2s[HID];

    const int tid = threadIdx.x;

    for (int idx = tid; idx < HID * 32; idx += NTHREADS) {
        float v = W1[idx];
        int h = idx >> 5, k = idx & 31;
        W1row[h][k] = v;
        if (k >= 16) BTl[(k - 16) * 132 + h] = v;
    }
    if (tid < HID) { b1s[tid] = b1[tid]; w2s[tid] = w2[tid]; }

    const int wave = tid >> 6;
    const int lane = tid & 63;
    const int grp  = lane >> 4;
    const int j    = lane & 15;       // lane's row/col index
    const int smp  = wave * 4 + grp;  // sample within block
    const long long s0 = (long long)blockIdx.x * SPB;

    // y sample into registers (VMEM; off the DS pipe)
    float q[16], qd[16];
    {
        const float4* y4 = (const float4*)(y + (s0 + smp) * 32);
        float4 t0=y4[0],t1=y4[1],t2=y4[2],t3=y4[3],t4=y4[4],t5=y4[5],t6=y4[6],t7=y4[7];
        q[0]=t0.x;q[1]=t0.y;q[2]=t0.z;q[3]=t0.w;  q[4]=t1.x;q[5]=t1.y;q[6]=t1.z;q[7]=t1.w;
        q[8]=t2.x;q[9]=t2.y;q[10]=t2.z;q[11]=t2.w; q[12]=t3.x;q[13]=t3.y;q[14]=t3.z;q[15]=t3.w;
        qd[0]=t4.x;qd[1]=t4.y;qd[2]=t4.z;qd[3]=t4.w; qd[4]=t5.x;qd[5]=t5.y;qd[6]=t5.z;qd[7]=t5.w;
        qd[8]=t6.x;qd[9]=t6.y;qd[10]=t6.z;qd[11]=t6.w; qd[12]=t7.x;qd[13]=t7.y;qd[14]=t7.z;qd[15]=t7.w;
    }

    __syncthreads();

    float Mrow[16];
#pragma unroll
    for (int i = 0; i < 16; ++i) Mrow[i] = (i == j) ? 1.0f : 0.0f;
    float prhs[16];
#pragma unroll
    for (int i = 0; i < 16; ++i) prhs[i] = 0.0f;

    float* ss = &sstg[smp * SSTR];

#pragma unroll 1
    for (int hb = 0; hb < HID / 16; ++hb) {
        const int hj = (hb << 4) + j;

        // ---- phase 1: lane's hidden unit hj; W1 row from LDS (proven v2 path) ----
        const float4* wr4 = (const float4*)&W1row[hj][0];
        float4 a0 = wr4[0], a1 = wr4[1], a2 = wr4[2], a3 = wr4[3];
        float4 c0 = wr4[4], c1 = wr4[5], c2 = wr4[6], c3 = wr4[7];

        float z = b1s[hj];
        float aqd = 0.0f;
        DOT4(z, a0, q, 0)   DOT4(z, a1, q, 4)   DOT4(z, a2, q, 8)   DOT4(z, a3, q, 12)
        DOT4(z, c0, qd, 0)  DOT4(z, c1, qd, 4)  DOT4(z, c2, qd, 8)  DOT4(z, c3, qd, 12)
        DOT4(aqd, a0, qd, 0) DOT4(aqd, a1, qd, 4) DOT4(aqd, a2, qd, 8) DOT4(aqd, a3, qd, 12)

        // branch-free tanh: r = 2/(e^{2z}+1), t = 1-r, sech^2 = r(2-r)
        float e = __expf(2.0f * z);
        float r = 2.0f * __builtin_amdgcn_rcpf(e + 1.0f);
        float t = 1.0f - r;
        float u = w2s[hj] * (r * (2.0f - r));
        float s = -2.0f * t * u;
        float sp = s * aqd;

        ss[j] = s;   // only s goes through LDS (same-wave write->read)

        // fused rhs partials: prhs[jj] += u*A[hj][jj] - sp*B[hj][jj]
#define PRH(jj, Av, Bv, c)  prhs[jj] = fmaf(u, (Av).c, fmaf(-sp, (Bv).c, prhs[jj]));
        PRH(0,a0,c0,x)  PRH(1,a0,c0,y)  PRH(2,a0,c0,z)  PRH(3,a0,c0,w)
        PRH(4,a1,c1,x)  PRH(5,a1,c1,y)  PRH(6,a1,c1,z)  PRH(7,a1,c1,w)
        PRH(8,a2,c2,x)  PRH(9,a2,c2,y)  PRH(10,a2,c2,z) PRH(11,a2,c2,w)
        PRH(12,a3,c3,x) PRH(13,a3,c3,y) PRH(14,a3,c3,z) PRH(15,a3,c3,w)
#undef PRH

        // ---- phase 2: Mrow[i] += s_h * B[h][j] * B[h][i] over this hb's 16 h's ----
        const float* base2 = W1 + (hb << 4) * 32 + 16;   // wave-uniform -> s_load
        const float* bt = &BTl[j * 132 + (hb << 4)];
#pragma unroll
        for (int c = 0; c < 4; ++c) {
            float4 sv = *(const float4*)&ss[4 * c];      // group-broadcast
            float4 bv = *(const float4*)&bt[4 * c];      // 2-way alias = free
#define MACC(cc, hh)                                                    \
            {                                                           \
                float sB = sv.cc * bv.cc;                               \
                const float* Br = base2 + (4 * c + (hh)) * 32;          \
                _Pragma("unroll")                                       \
                for (int i = 0; i < 16; ++i)                            \
                    Mrow[i] = fmaf(sB, Br[i], Mrow[i]);                 \
            }
            MACC(x, 0) MACC(y, 1) MACC(z, 2) MACC(w, 3)
#undef MACC
        }
    }

    // ---- rhs: transpose-reduce prhs across the 16-lane group (shfl_xor butterfly) ----
    float rhs;
    {
        float a8[8], a4[4], a2[2];
        const bool h8 = (j & 8) != 0;
        const bool h4 = (j & 4) != 0;
        const bool h2 = (j & 2) != 0;
        const bool h1 = (j & 1) != 0;
#pragma unroll
        for (int i = 0; i < 8; ++i) {
            float send = h8 ? prhs[i] : prhs[i + 8];
            float recv = __shfl_xor(send, 8, 16);
            a8[i] = (h8 ? prhs[i + 8] : prhs[i]) + recv;
        }
#pragma unroll
        for (int i = 0; i < 4; ++i) {
            float send = h4 ? a8[i] : a8[i + 4];
            float recv = __shfl_xor(send, 4, 16);
            a4[i] = (h4 ? a8[i + 4] : a8[i]) + recv;
        }
#pragma unroll
        for (int i = 0; i < 2; ++i) {
            float send = h2 ? a4[i] : a4[i + 2];
            float recv = __shfl_xor(send, 2, 16);
            a2[i] = (h2 ? a4[i + 2] : a4[i]) + recv;
        }
        {
            float send = h1 ? a2[0] : a2[1];
            float recv = __shfl_xor(send, 1, 16);
            rhs = (h1 ? a2[1] : a2[0]) + recv;
        }
    }

    // ---- solve M x = rhs: non-normalizing Gauss-Jordan, triangular skip ----
    float diagj = 1.0f;
#pragma unroll
    for (int k = 0; k < 16; ++k) {
        float piv = __shfl(Mrow[k], k, 16);
        float invp = __builtin_amdgcn_rcpf(piv);
        invp = invp * (2.0f - piv * invp);          // 1 NR step
        float factor = Mrow[k] * invp;
        factor = (j == k) ? 0.0f : factor;
        diagj  = (j == k) ? piv : diagj;
#pragma unroll
        for (int i = k; i < 16; ++i) {
            float mki = __shfl(Mrow[i], k, 16);
            Mrow[i] = fmaf(-factor, mki, Mrow[i]);
        }
        float rk = __shfl(rhs, k, 16);
        rhs = fmaf(-factor, rk, rhs);
    }
    float invd = __builtin_amdgcn_rcpf(diagj);
    invd = invd * (2.0f - diagj * invd);
    out[(s0 + smp) * DIMQ + j] = rhs * invd;
}

extern "C" void kernel_launch(void* const* d_in, const int* in_sizes, int n_in,
                              void* d_out, int out_size, void* d_ws, size_t ws_size,
                              hipStream_t stream) {
    const float* y  = (const float*)d_in[0];
    const float* W1 = (const float*)d_in[1];
    const float* b1 = (const float*)d_in[2];
    const float* w2 = (const float*)d_in[3];
    float* out = (float*)d_out;
    const int batch = in_sizes[0] / 32;          // 32768
    const int blocks = (batch + SPB - 1) / SPB;  // 1024
    lag_accel_kernel<<<blocks, NTHREADS, 0, stream>>>(y, W1, b1, w2, out);
}

// Round 6
// 35.563 us; speedup vs baseline: 2.1590x; 1.3829x over previous
//
#include <hip/hip_runtime.h>
#include <math.h>

#define DIMQ 16
#define HID  128
#define SPB  32          // samples per block (8 waves x 4 samples/wave)
#define NTHREADS 512

typedef __attribute__((ext_vector_type(8))) short bf16x8;   // 8 bf16 (4 VGPRs)
typedef __attribute__((ext_vector_type(4))) float f32x4;    // MFMA acc

// LDS layout (bytes). scr overlays the phase-1/M-phase regions AFTER a barrier.
#define OFF_W1ROW 0          // f32 [128][36]   = 18432
#define OFF_BT    18432      // bf16 [16][136]  =  4352  -> 22784
#define OFF_SSTG  22784      // bf16 [32][144]  =  9216  -> 32000
#define OFF_SCR   0          // f32 [8][4][16][17] = 34816 (post-barrier)
#define OFF_B1    34816      // f32[128]
#define OFF_W2    35328      // f32[128]
#define LDS_BYTES 35840

__device__ __forceinline__ float bf2f(short s) {
    union { unsigned u; float f; } cv;
    cv.u = ((unsigned)(unsigned short)s) << 16;
    return cv.f;
}
__device__ __forceinline__ short f2bf(float f) {
    __bf16 h = (__bf16)f;            // compiler emits hw cvt (RNE), pairs into cvt_pk
    return __builtin_bit_cast(short, h);
}

#define DOT4(acc, v, arr, base)                    \
    acc = fmaf((v).x, arr[(base) + 0], acc);       \
    acc = fmaf((v).y, arr[(base) + 1], acc);       \
    acc = fmaf((v).z, arr[(base) + 2], acc);       \
    acc = fmaf((v).w, arr[(base) + 3], acc);

__global__ __launch_bounds__(NTHREADS, 4)
void lag_accel_kernel(const float* __restrict__ y,    // [BATCH][32]
                      const float* __restrict__ W1,   // [128][32]
                      const float* __restrict__ b1,   // [128]
                      const float* __restrict__ w2,   // [128]
                      float* __restrict__ out)        // [BATCH][16]
{
    __shared__ __align__(16) char smem[LDS_BYTES];
    float* W1row = (float*)(smem + OFF_W1ROW);   // [128][36] f32
    short* BT    = (short*)(smem + OFF_BT);      // [16][136] bf16: BT[j][h] = W1[h][16+j]
    short* sstg  = (short*)(smem + OFF_SSTG);    // [32][144] bf16 s-values
    float* b1s   = (float*)(smem + OFF_B1);
    float* w2s   = (float*)(smem + OFF_W2);

    const int tid = threadIdx.x;

    for (int idx = tid; idx < HID * 32; idx += NTHREADS) {
        float v = W1[idx];
        int h = idx >> 5, k = idx & 31;
        W1row[h * 36 + k] = v;
        if (k >= 16) BT[(k - 16) * 136 + h] = f2bf(v);
    }
    if (tid < HID) { b1s[tid] = b1[tid]; w2s[tid] = w2[tid]; }

    const int wave = tid >> 6;
    const int lane = tid & 63;
    const int grp  = lane >> 4;       // sample-within-wave (phase1/solve); k-subchunk (M-phase)
    const int j    = lane & 15;       // row/col index
    const int smp  = wave * 4 + grp;  // sample within block
    const long long s0 = (long long)blockIdx.x * SPB;

    // y sample into registers (VMEM; off the DS pipe)
    float q[16], qd[16];
    {
        const float4* y4 = (const float4*)(y + (s0 + smp) * 32);
        float4 t0=y4[0],t1=y4[1],t2=y4[2],t3=y4[3],t4=y4[4],t5=y4[5],t6=y4[6],t7=y4[7];
        q[0]=t0.x;q[1]=t0.y;q[2]=t0.z;q[3]=t0.w;  q[4]=t1.x;q[5]=t1.y;q[6]=t1.z;q[7]=t1.w;
        q[8]=t2.x;q[9]=t2.y;q[10]=t2.z;q[11]=t2.w; q[12]=t3.x;q[13]=t3.y;q[14]=t3.z;q[15]=t3.w;
        qd[0]=t4.x;qd[1]=t4.y;qd[2]=t4.z;qd[3]=t4.w; qd[4]=t5.x;qd[5]=t5.y;qd[6]=t5.z;qd[7]=t5.w;
        qd[8]=t6.x;qd[9]=t6.y;qd[10]=t6.z;qd[11]=t6.w; qd[12]=t7.x;qd[13]=t7.y;qd[14]=t7.z;qd[15]=t7.w;
    }

    __syncthreads();

    float prhs[16];
#pragma unroll
    for (int i = 0; i < 16; ++i) prhs[i] = 0.0f;

    short* ssmp = sstg + smp * 144;

    // ---- phase 1: all 128 hidden units (lane handles h = hb*16+j), f32 throughout ----
#pragma unroll 1
    for (int hb = 0; hb < HID / 16; ++hb) {
        const int hj = (hb << 4) + j;
        const float4* wr4 = (const float4*)&W1row[hj * 36];
        float4 a0 = wr4[0], a1 = wr4[1], a2 = wr4[2], a3 = wr4[3];
        float4 c0 = wr4[4], c1 = wr4[5], c2 = wr4[6], c3 = wr4[7];

        float z = b1s[hj];
        float aqd = 0.0f;
        DOT4(z, a0, q, 0)   DOT4(z, a1, q, 4)   DOT4(z, a2, q, 8)   DOT4(z, a3, q, 12)
        DOT4(z, c0, qd, 0)  DOT4(z, c1, qd, 4)  DOT4(z, c2, qd, 8)  DOT4(z, c3, qd, 12)
        DOT4(aqd, a0, qd, 0) DOT4(aqd, a1, qd, 4) DOT4(aqd, a2, qd, 8) DOT4(aqd, a3, qd, 12)

        // branch-free tanh: r = 2/(e^{2z}+1), t = 1-r, sech^2 = r(2-r)
        float e = __expf(2.0f * z);
        float r = 2.0f * __builtin_amdgcn_rcpf(e + 1.0f);
        float t = 1.0f - r;
        float u = w2s[hj] * (r * (2.0f - r));
        float s = -2.0f * t * u;
        float sp = s * aqd;

        ssmp[(hb << 4) + j] = f2bf(s);    // s -> bf16 for the MFMA phase

        // fused rhs partials: prhs[jj] += u*A[hj][jj] - sp*B[hj][jj]
#define PRH(jj, Av, Bv, c)  prhs[jj] = fmaf(u, (Av).c, fmaf(-sp, (Bv).c, prhs[jj]));
        PRH(0,a0,c0,x)  PRH(1,a0,c0,y)  PRH(2,a0,c0,z)  PRH(3,a0,c0,w)
        PRH(4,a1,c1,x)  PRH(5,a1,c1,y)  PRH(6,a1,c1,z)  PRH(7,a1,c1,w)
        PRH(8,a2,c2,x)  PRH(9,a2,c2,y)  PRH(10,a2,c2,z) PRH(11,a2,c2,w)
        PRH(12,a3,c3,x) PRH(13,a3,c3,y) PRH(14,a3,c3,z) PRH(15,a3,c3,w)
#undef PRH
    }

    // ---- M = I + B~^T diag(s) B~ via MFMA: 4 K-chunks x 4 samples per wave ----
    // D layout (m89-verified): col = lane&15, row = 4*(lane>>4)+reg.
    f32x4 acc[4];
    {
        f32x4 ident;
#pragma unroll
        for (int r = 0; r < 4; ++r) ident[r] = ((grp << 2) + r == j) ? 1.0f : 0.0f;
#pragma unroll
        for (int gs = 0; gs < 4; ++gs) acc[gs] = ident;
    }

#pragma unroll
    for (int kc = 0; kc < 4; ++kc) {
        // B-frag: lane covers col n=j, k-elems h = 32*kc + 8*grp + e  (same bytes feed A)
        bf16x8 bfrag = *(const bf16x8*)&BT[j * 136 + (kc << 5) + (grp << 3)];
        float Bf[8];
#pragma unroll
        for (int e = 0; e < 8; ++e) Bf[e] = bf2f(bfrag[e]);
#pragma unroll
        for (int gs = 0; gs < 4; ++gs) {
            bf16x8 sfrag = *(const bf16x8*)&sstg[(wave * 4 + gs) * 144 + (kc << 5) + (grp << 3)];
            bf16x8 afrag;
#pragma unroll
            for (int e = 0; e < 8; ++e) afrag[e] = f2bf(bf2f(sfrag[e]) * Bf[e]);
            acc[gs] = __builtin_amdgcn_mfma_f32_16x16x32_bf16(afrag, bfrag, acc[gs], 0, 0, 0);
        }
    }

    // ---- rhs: transpose-reduce prhs across the 16-lane group (shfl_xor butterfly) ----
    float rhs;
    {
        float a8[8], a4[4], a2[2];
        const bool h8 = (j & 8) != 0;
        const bool h4 = (j & 4) != 0;
        const bool h2 = (j & 2) != 0;
        const bool h1 = (j & 1) != 0;
#pragma unroll
        for (int i = 0; i < 8; ++i) {
            float send = h8 ? prhs[i] : prhs[i + 8];
            float recv = __shfl_xor(send, 8, 16);
            a8[i] = (h8 ? prhs[i + 8] : prhs[i]) + recv;
        }
#pragma unroll
        for (int i = 0; i < 4; ++i) {
            float send = h4 ? a8[i] : a8[i + 4];
            float recv = __shfl_xor(send, 4, 16);
            a4[i] = (h4 ? a8[i + 4] : a8[i]) + recv;
        }
#pragma unroll
        for (int i = 0; i < 2; ++i) {
            float send = h2 ? a4[i] : a4[i + 2];
            float recv = __shfl_xor(send, 2, 16);
            a2[i] = (h2 ? a4[i + 2] : a4[i]) + recv;
        }
        {
            float send = h1 ? a2[0] : a2[1];
            float recv = __shfl_xor(send, 1, 16);
            rhs = (h1 ? a2[1] : a2[0]) + recv;
        }
    }

    // ---- relayout M: MFMA D layout -> row-per-lane, via per-wave LDS scratch ----
    // Barrier: scr overlays W1row/BT/sstg, so all waves must be done reading them.
    __syncthreads();
    float* scrw = (float*)(smem + OFF_SCR) + wave * (4 * 272);   // [4][16][17] f32 per wave
#pragma unroll
    for (int gs = 0; gs < 4; ++gs)
#pragma unroll
        for (int r = 0; r < 4; ++r)
            scrw[gs * 272 + ((grp << 2) + r) * 17 + j] = acc[gs][r];

    float Mrow[16];
#pragma unroll
    for (int i = 0; i < 16; ++i) Mrow[i] = scrw[grp * 272 + j * 17 + i];

    // ---- solve M x = rhs: non-normalizing Gauss-Jordan, triangular skip ----
    float diagj = 1.0f;
#pragma unroll
    for (int k = 0; k < 16; ++k) {
        float piv = __shfl(Mrow[k], k, 16);
        float invp = __builtin_amdgcn_rcpf(piv);
        invp = invp * (2.0f - piv * invp);          // 1 NR step
        float factor = Mrow[k] * invp;
        factor = (j == k) ? 0.0f : factor;
        diagj  = (j == k) ? piv : diagj;
#pragma unroll
        for (int i = k; i < 16; ++i) {
            float mki = __shfl(Mrow[i], k, 16);
            Mrow[i] = fmaf(-factor, mki, Mrow[i]);
        }
        float rk = __shfl(rhs, k, 16);
        rhs = fmaf(-factor, rk, rhs);
    }
    float invd = __builtin_amdgcn_rcpf(diagj);
    invd = invd * (2.0f - diagj * invd);
    out[(s0 + smp) * DIMQ + j] = rhs * invd;
}

extern "C" void kernel_launch(void* const* d_in, const int* in_sizes, int n_in,
                              void* d_out, int out_size, void* d_ws, size_t ws_size,
                              hipStream_t stream) {
    const float* y  = (const float*)d_in[0];
    const float* W1 = (const float*)d_in[1];
    const float* b1 = (const float*)d_in[2];
    const float* w2 = (const float*)d_in[3];
    float* out = (float*)d_out;
    const int batch = in_sizes[0] / 32;          // 32768
    const int blocks = (batch + SPB - 1) / SPB;  // 1024
    lag_accel_kernel<<<blocks, NTHREADS, 0, stream>>>(y, W1, b1, w2, out);
}

// Round 7
// 30.748 us; speedup vs baseline: 2.4970x; 1.1566x over previous
//
#include <hip/hip_runtime.h>
#include <math.h>

#define DIMQ 16
#define HID  128
#define SPB  32          // samples per block (8 waves x 4 samples/wave)
#define NTHREADS 512

typedef __attribute__((ext_vector_type(8))) short bf16x8;   // 8 bf16 (4 VGPRs)
typedef __attribute__((ext_vector_type(4))) float f32x4;    // MFMA acc

// LDS layout (bytes). Mscr overlays ALL phase-1 regions after barrier #1.
#define OFF_W1ROW 0          // f32 [128][36]  = 18432
#define OFF_BT    18432      // bf16 [16][136] =  4352 -> 22784
#define OFF_SSTG  22784      // bf16 [32][144] =  9216 -> 32000
#define OFF_B1    32000      // f32[128] -> 32512
#define OFF_W2    32512      // f32[128] -> 33024
#define OFF_MSCR  0          // f32 32*320 = 40960 (post-barrier overlay)
#define LDS_BYTES 40960      // exactly 160KB/4 -> 4 blocks/CU

__device__ __forceinline__ float bf2f(short s) {
    union { unsigned u; float f; } cv;
    cv.u = ((unsigned)(unsigned short)s) << 16;
    return cv.f;
}
__device__ __forceinline__ short f2bf(float f) {
    __bf16 h = (__bf16)f;
    return __builtin_bit_cast(short, h);
}
// XOR-swizzle inside each sample's 320-f32 M-scratch: keeps b128 contiguity
// (xor bits >= f32-bit2) while de-aliasing banks across samples.
__device__ __forceinline__ int mswz(int s, int off) {
    return s * 320 + (off ^ ((s & 7) << 2));
}

#define DOT4(acc, v, arr, base)                    \
    acc = fmaf((v).x, arr[(base) + 0], acc);       \
    acc = fmaf((v).y, arr[(base) + 1], acc);       \
    acc = fmaf((v).z, arr[(base) + 2], acc);       \
    acc = fmaf((v).w, arr[(base) + 3], acc);

__global__ __launch_bounds__(NTHREADS, 4)
void lag_accel_kernel(const float* __restrict__ y,    // [BATCH][32]
                      const float* __restrict__ W1,   // [128][32]
                      const float* __restrict__ b1,   // [128]
                      const float* __restrict__ w2,   // [128]
                      float* __restrict__ out)        // [BATCH][16]
{
    __shared__ __align__(16) char smem[LDS_BYTES];
    float* W1row = (float*)(smem + OFF_W1ROW);   // [128][36] f32
    short* BT    = (short*)(smem + OFF_BT);      // [16][136] bf16: BT[j][h] = W1[h][16+j]
    short* sstg  = (short*)(smem + OFF_SSTG);    // [32][144] bf16 s-values
    float* b1s   = (float*)(smem + OFF_B1);
    float* w2s   = (float*)(smem + OFF_W2);

    const int tid = threadIdx.x;

    for (int idx = tid; idx < HID * 32; idx += NTHREADS) {
        float v = W1[idx];
        int h = idx >> 5, k = idx & 31;
        W1row[h * 36 + k] = v;
        if (k >= 16) BT[(k - 16) * 136 + h] = f2bf(v);
    }
    if (tid < HID) { b1s[tid] = b1[tid]; w2s[tid] = w2[tid]; }

    const int wave = tid >> 6;
    const int lane = tid & 63;
    const int grp  = lane >> 4;       // sample-within-wave (phase1); k-subchunk (MFMA)
    const int j    = lane & 15;       // row/col index
    const int smp  = wave * 4 + grp;  // sample within block
    const long long s0 = (long long)blockIdx.x * SPB;

    // y sample into registers (VMEM; off the DS pipe)
    float q[16], qd[16];
    {
        const float4* y4 = (const float4*)(y + (s0 + smp) * 32);
        float4 t0=y4[0],t1=y4[1],t2=y4[2],t3=y4[3],t4=y4[4],t5=y4[5],t6=y4[6],t7=y4[7];
        q[0]=t0.x;q[1]=t0.y;q[2]=t0.z;q[3]=t0.w;  q[4]=t1.x;q[5]=t1.y;q[6]=t1.z;q[7]=t1.w;
        q[8]=t2.x;q[9]=t2.y;q[10]=t2.z;q[11]=t2.w; q[12]=t3.x;q[13]=t3.y;q[14]=t3.z;q[15]=t3.w;
        qd[0]=t4.x;qd[1]=t4.y;qd[2]=t4.z;qd[3]=t4.w; qd[4]=t5.x;qd[5]=t5.y;qd[6]=t5.z;qd[7]=t5.w;
        qd[8]=t6.x;qd[9]=t6.y;qd[10]=t6.z;qd[11]=t6.w; qd[12]=t7.x;qd[13]=t7.y;qd[14]=t7.z;qd[15]=t7.w;
    }

    __syncthreads();

    float prhs[16];
#pragma unroll
    for (int i = 0; i < 16; ++i) prhs[i] = 0.0f;

    short* ssmp = sstg + smp * 144;

    // ---- phase 1: all 128 hidden units (lane handles h = hb*16+j), f32 throughout ----
#pragma unroll 1
    for (int hb = 0; hb < HID / 16; ++hb) {
        const int hj = (hb << 4) + j;
        const float4* wr4 = (const float4*)&W1row[hj * 36];
        float4 a0 = wr4[0], a1 = wr4[1], a2 = wr4[2], a3 = wr4[3];
        float4 c0 = wr4[4], c1 = wr4[5], c2 = wr4[6], c3 = wr4[7];

        float z = b1s[hj];
        float aqd = 0.0f;
        DOT4(z, a0, q, 0)   DOT4(z, a1, q, 4)   DOT4(z, a2, q, 8)   DOT4(z, a3, q, 12)
        DOT4(z, c0, qd, 0)  DOT4(z, c1, qd, 4)  DOT4(z, c2, qd, 8)  DOT4(z, c3, qd, 12)
        DOT4(aqd, a0, qd, 0) DOT4(aqd, a1, qd, 4) DOT4(aqd, a2, qd, 8) DOT4(aqd, a3, qd, 12)

        // branch-free tanh: r = 2/(e^{2z}+1), t = 1-r, sech^2 = r(2-r)
        float e = __expf(2.0f * z);
        float r = 2.0f * __builtin_amdgcn_rcpf(e + 1.0f);
        float t = 1.0f - r;
        float u = w2s[hj] * (r * (2.0f - r));
        float s = -2.0f * t * u;
        float sp = s * aqd;

        ssmp[(hb << 4) + j] = f2bf(s);    // s -> bf16 for the MFMA phase

        // fused rhs partials: prhs[jj] += u*A[hj][jj] - sp*B[hj][jj]
#define PRH(jj, Av, Bv, c)  prhs[jj] = fmaf(u, (Av).c, fmaf(-sp, (Bv).c, prhs[jj]));
        PRH(0,a0,c0,x)  PRH(1,a0,c0,y)  PRH(2,a0,c0,z)  PRH(3,a0,c0,w)
        PRH(4,a1,c1,x)  PRH(5,a1,c1,y)  PRH(6,a1,c1,z)  PRH(7,a1,c1,w)
        PRH(8,a2,c2,x)  PRH(9,a2,c2,y)  PRH(10,a2,c2,z) PRH(11,a2,c2,w)
        PRH(12,a3,c3,x) PRH(13,a3,c3,y) PRH(14,a3,c3,z) PRH(15,a3,c3,w)
#undef PRH
    }

    // ---- M = I + B~^T diag(s) B~ via MFMA (D layout: col=lane&15, row=4*(lane>>4)+reg) ----
    f32x4 acc[4];
    {
        f32x4 ident;
#pragma unroll
        for (int r = 0; r < 4; ++r) ident[r] = ((grp << 2) + r == j) ? 1.0f : 0.0f;
#pragma unroll
        for (int gs = 0; gs < 4; ++gs) acc[gs] = ident;
    }
#pragma unroll
    for (int kc = 0; kc < 4; ++kc) {
        bf16x8 bfrag = *(const bf16x8*)&BT[j * 136 + (kc << 5) + (grp << 3)];
        float Bf[8];
#pragma unroll
        for (int e = 0; e < 8; ++e) Bf[e] = bf2f(bfrag[e]);
#pragma unroll
        for (int gs = 0; gs < 4; ++gs) {
            bf16x8 sfrag = *(const bf16x8*)&sstg[(wave * 4 + gs) * 144 + (kc << 5) + (grp << 3)];
            bf16x8 afrag;
#pragma unroll
            for (int e = 0; e < 8; ++e) afrag[e] = f2bf(bf2f(sfrag[e]) * Bf[e]);
            acc[gs] = __builtin_amdgcn_mfma_f32_16x16x32_bf16(afrag, bfrag, acc[gs], 0, 0, 0);
        }
    }

    // ---- rhs: transpose-reduce prhs across the 16-lane group (shfl_xor butterfly) ----
    float rhs;
    {
        float a8[8], a4[4], a2[2];
        const bool h8 = (j & 8) != 0;
        const bool h4 = (j & 4) != 0;
        const bool h2 = (j & 2) != 0;
        const bool h1 = (j & 1) != 0;
#pragma unroll
        for (int i = 0; i < 8; ++i) {
            float send = h8 ? prhs[i] : prhs[i + 8];
            float recv = __shfl_xor(send, 8, 16);
            a8[i] = (h8 ? prhs[i + 8] : prhs[i]) + recv;
        }
#pragma unroll
        for (int i = 0; i < 4; ++i) {
            float send = h4 ? a8[i] : a8[i + 4];
            float recv = __shfl_xor(send, 4, 16);
            a4[i] = (h4 ? a8[i + 4] : a8[i]) + recv;
        }
#pragma unroll
        for (int i = 0; i < 2; ++i) {
            float send = h2 ? a4[i] : a4[i + 2];
            float recv = __shfl_xor(send, 2, 16);
            a2[i] = (h2 ? a4[i + 2] : a4[i]) + recv;
        }
        {
            float send = h1 ? a2[0] : a2[1];
            float recv = __shfl_xor(send, 1, 16);
            rhs = (h1 ? a2[1] : a2[0]) + recv;
        }
    }

    // ---- barrier #1: all reads of W1row/BT/sstg done; Mscr overlays them ----
    __syncthreads();
    float* Mscr = (float*)(smem + OFF_MSCR);

    // M is symmetric: D(rows 4grp..4grp+3, col j) == M[j][4grp..4grp+3] -> ONE b128 write/sample.
#pragma unroll
    for (int gs = 0; gs < 4; ++gs) {
        float4 v;
        v.x = acc[gs][0]; v.y = acc[gs][1]; v.z = acc[gs][2]; v.w = acc[gs][3];
        *(float4*)&Mscr[mswz(wave * 4 + gs, j * 20 + (grp << 2))] = v;
    }
    Mscr[mswz(smp, j * 20 + 16)] = rhs;      // rhs_j in col 16 of row j

    __syncthreads();   // barrier #2: scratch complete

    // ---- solve: waves 0,1 handle 16 samples each (4 lanes/sample, 4 rows/lane) ----
    if (wave >= 2) return;
    const int sl = lane & 15;            // sample within this wave's half
    const int rb = lane >> 4;            // row block (rows 4rb..4rb+3)
    const int s  = wave * 16 + sl;       // sample within block

    float M4[4][16], r4[4], d4[4];
#pragma unroll
    for (int r = 0; r < 4; ++r) {
        const int ro = (4 * rb + r) * 20;
        float4 v0 = *(const float4*)&Mscr[mswz(s, ro + 0)];
        float4 v1 = *(const float4*)&Mscr[mswz(s, ro + 4)];
        float4 v2 = *(const float4*)&Mscr[mswz(s, ro + 8)];
        float4 v3 = *(const float4*)&Mscr[mswz(s, ro + 12)];
        M4[r][0]=v0.x; M4[r][1]=v0.y; M4[r][2]=v0.z; M4[r][3]=v0.w;
        M4[r][4]=v1.x; M4[r][5]=v1.y; M4[r][6]=v1.z; M4[r][7]=v1.w;
        M4[r][8]=v2.x; M4[r][9]=v2.y; M4[r][10]=v2.z; M4[r][11]=v2.w;
        M4[r][12]=v3.x; M4[r][13]=v3.y; M4[r][14]=v3.z; M4[r][15]=v3.w;
        r4[r] = Mscr[mswz(s, ro + 16)];
        d4[r] = 1.0f;
    }

    // Gauss-Jordan, non-normalizing, triangular skip; row k owned by lane sl+16*(k>>2), reg k&3.
#pragma unroll
    for (int k = 0; k < 16; ++k) {
        const int src = sl + ((k >> 2) << 4);            // k compile-time
        float piv = __shfl(M4[k & 3][k], src, 64);
        float rk  = __shfl(r4[k & 3], src, 64);
        float invp = __builtin_amdgcn_rcpf(piv);
        invp = invp * (2.0f - piv * invp);               // 1 NR step
        float f[4];
#pragma unroll
        for (int r = 0; r < 4; ++r) {
            float fr = M4[r][k] * invp;
            const bool isk = ((rb << 2) + r) == k;
            f[r]  = isk ? 0.0f : fr;
            d4[r] = isk ? piv : d4[r];
            r4[r] = fmaf(-f[r], rk, r4[r]);
        }
#pragma unroll
        for (int i = k + 1; i < 16; ++i) {
            float p = __shfl(M4[k & 3][i], src, 64);
            M4[0][i] = fmaf(-f[0], p, M4[0][i]);
            M4[1][i] = fmaf(-f[1], p, M4[1][i]);
            M4[2][i] = fmaf(-f[2], p, M4[2][i]);
            M4[3][i] = fmaf(-f[3], p, M4[3][i]);
        }
    }

    float4 xo;
    {
        float i0 = __builtin_amdgcn_rcpf(d4[0]); i0 = i0 * (2.0f - d4[0] * i0);
        float i1 = __builtin_amdgcn_rcpf(d4[1]); i1 = i1 * (2.0f - d4[1] * i1);
        float i2 = __builtin_amdgcn_rcpf(d4[2]); i2 = i2 * (2.0f - d4[2] * i2);
        float i3 = __builtin_amdgcn_rcpf(d4[3]); i3 = i3 * (2.0f - d4[3] * i3);
        xo.x = r4[0] * i0; xo.y = r4[1] * i1; xo.z = r4[2] * i2; xo.w = r4[3] * i3;
    }
    *(float4*)&out[(s0 + s) * DIMQ + (rb << 2)] = xo;
}

extern "C" void kernel_launch(void* const* d_in, const int* in_sizes, int n_in,
                              void* d_out, int out_size, void* d_ws, size_t ws_size,
                              hipStream_t stream) {
    const float* y  = (const float*)d_in[0];
    const float* W1 = (const float*)d_in[1];
    const float* b1 = (const float*)d_in[2];
    const float* w2 = (const float*)d_in[3];
    float* out = (float*)d_out;
    const int batch = in_sizes[0] / 32;          // 32768
    const int blocks = (batch + SPB - 1) / SPB;  // 1024
    lag_accel_kernel<<<blocks, NTHREADS, 0, stream>>>(y, W1, b1, w2, out);
}

// Round 9
// 23.581 us; speedup vs baseline: 3.2560x; 1.3040x over previous
//
#include <hip/hip_runtime.h>
#include <math.h>

#define DIMQ 16
#define HID  128
#define SPB  32          // samples per block (8 waves; each wave owns ONE 16-h tile, all samples)
#define NTHREADS 512

typedef __attribute__((ext_vector_type(8))) short bf16x8;   // MFMA A/B frag (4 VGPRs)
typedef __attribute__((ext_vector_type(4))) short s16x4;    // packed b64 store
typedef __attribute__((ext_vector_type(4))) float f32x4;    // MFMA acc

// bf16 row strides (elements)
#define ASTR 280         // ABT[16][280]: [A^T | B^T], 560B row -> 12-bank skew
#define USTR 280         // usp[32][280]: u at h'=0..127, -sp at h'=128..255
#define SSTR 136         // sst[32][136]: s values (v7-validated stride)

// LDS layout (bytes). Mscr overlays everything below it AFTER barrier #2.
#define OFF_WBF  0       // bf16[128][32] = 8192
#define OFF_YBF  8192    // bf16[32][32]  = 2048  -> 10240
#define OFF_ABT  10240   // bf16[16][280] = 8960  -> 19200
#define OFF_USP  19200   // bf16[32][280] = 17920 -> 37120
#define OFF_SST  37120   // bf16[32][136] = 8704  -> 45824
#define OFF_B1   45824   // f32[128] -> 46336
#define OFF_W2   46336   // f32[128] -> 46848
#define OFF_MSCR 0       // f32 32*320 = 40960 (post-barrier-2 overlay)
#define LDS_BYTES 46848  // 3 blocks/CU

__device__ __forceinline__ float bf2f(short s) {
    union { unsigned u; float f; } cv;
    cv.u = ((unsigned)(unsigned short)s) << 16;
    return cv.f;
}
__device__ __forceinline__ short f2bf(float f) {
    __bf16 h = (__bf16)f;
    return __builtin_bit_cast(short, h);
}
// XOR-swizzle inside each sample's 320-f32 M-scratch (v7-validated).
__device__ __forceinline__ int mswz(int s, int off) {
    return s * 320 + (off ^ ((s & 7) << 2));
}

__global__ __launch_bounds__(NTHREADS, 3)
void lag_accel_kernel(const float* __restrict__ y,    // [BATCH][32]
                      const float* __restrict__ W1,   // [128][32]
                      const float* __restrict__ b1,   // [128]
                      const float* __restrict__ w2,   // [128]
                      float* __restrict__ out)        // [BATCH][16]
{
    __shared__ __align__(16) char smem[LDS_BYTES];
    short* Wbf = (short*)(smem + OFF_WBF);   // [128][32] bf16 row-major W1
    short* Ybf = (short*)(smem + OFF_YBF);   // [32][32]  bf16 sample-major y
    short* ABT = (short*)(smem + OFF_ABT);   // [16][280] bf16: [j][h]=A[h][j], [j][128+h]=B[h][j]
    short* usp = (short*)(smem + OFF_USP);   // [32][280] bf16: u / -sp
    short* sst = (short*)(smem + OFF_SST);   // [32][136] bf16: s
    float* b1s = (float*)(smem + OFF_B1);
    float* w2s = (float*)(smem + OFF_W2);

    const int tid = threadIdx.x;
    const long long s0 = (long long)blockIdx.x * SPB;

    // ---- init staging: W1 (row-major bf16 + transposed bf16), y bf16, b1, w2 ----
    for (int idx = tid; idx < HID * 32; idx += NTHREADS) {
        float v = W1[idx];
        int h = idx >> 5, k = idx & 31;
        short bv = f2bf(v);
        Wbf[h * 32 + k] = bv;
        if (k < 16) ABT[k * ASTR + h] = bv;
        else        ABT[(k - 16) * ASTR + 128 + h] = bv;
    }
    for (int idx = tid; idx < SPB * 32; idx += NTHREADS)
        Ybf[idx] = f2bf(y[s0 * 32 + idx]);
    if (tid < HID) { b1s[tid] = b1[tid]; w2s[tid] = w2[tid]; }

    const int wave = tid >> 6;
    const int lane = tid & 63;
    const int grp  = lane >> 4;      // MFMA quadrant (k-slice / D row-block)
    const int j    = lane & 15;      // MFMA m/n index
    const int ht   = wave;           // this wave's h-tile (h = 16*ht .. 16*ht+15)

    __syncthreads();   // barrier 0: staging complete

    // ---- z/aqd GEMM: z = [A|B].y + b1 and aqd = [0|A].y (K=32), per h-tile ----
    bf16x8 aW = *(const bf16x8*)&Wbf[(ht * 16 + j) * 32 + (grp << 3)];
    // [0|A] operand: Aop[h][k] = (k>=16) ? A[h][k-16] : 0.
    // Lane grp holds k=8grp+e; grp=2 needs A[h][0..7] (Wbf off 0), grp=3 needs A[h][8..15] (off 8).
    bf16x8 aAl = *(const bf16x8*)&Wbf[(ht * 16 + j) * 32 + ((grp & 1) << 3)];
    bf16x8 aA;
#pragma unroll
    for (int e = 0; e < 8; ++e) aA[e] = (grp >= 2) ? aAl[e] : (short)0;

    float4 b1v = *(const float4*)&b1s[ht * 16 + (grp << 2)];
    float4 w2v = *(const float4*)&w2s[ht * 16 + (grp << 2)];

    f32x4 zacc[2], aacc[2];
    {
        f32x4 ci; ci[0] = b1v.x; ci[1] = b1v.y; ci[2] = b1v.z; ci[3] = b1v.w;
        f32x4 zf = {0.0f, 0.0f, 0.0f, 0.0f};
        bf16x8 yf0 = *(const bf16x8*)&Ybf[(0 * 16 + j) * 32 + (grp << 3)];
        bf16x8 yf1 = *(const bf16x8*)&Ybf[(1 * 16 + j) * 32 + (grp << 3)];
        zacc[0] = __builtin_amdgcn_mfma_f32_16x16x32_bf16(aW, yf0, ci, 0, 0, 0);
        zacc[1] = __builtin_amdgcn_mfma_f32_16x16x32_bf16(aW, yf1, ci, 0, 0, 0);
        aacc[0] = __builtin_amdgcn_mfma_f32_16x16x32_bf16(aA, yf0, zf, 0, 0, 0);
        aacc[1] = __builtin_amdgcn_mfma_f32_16x16x32_bf16(aA, yf1, zf, 0, 0, 0);
    }

    // ---- elementwise: t,u,s,sp per (h = 16ht+4grp+r, smp = 16st+j); stage bf16 ----
    const int h4 = ht * 16 + (grp << 2);
#define EWST(st)                                                         \
    {                                                                    \
        short su[4], sn[4], sv[4];                                       \
        _Pragma("unroll")                                                \
        for (int r = 0; r < 4; ++r) {                                    \
            float z  = zacc[st][r], aq = aacc[st][r];                    \
            float w2c = (r == 0) ? w2v.x : (r == 1) ? w2v.y               \
                       : (r == 2) ? w2v.z : w2v.w;                       \
            float e  = __expf(2.0f * z);                                 \
            float rr = 2.0f * __builtin_amdgcn_rcpf(e + 1.0f);           \
            float t  = 1.0f - rr;                                        \
            float u  = w2c * (rr * (2.0f - rr));                         \
            float s  = -2.0f * t * u;                                    \
            float sp = s * aq;                                           \
            su[r] = f2bf(u); sn[r] = f2bf(-sp); sv[r] = f2bf(s);         \
        }                                                                \
        const int smp2 = (st) * 16 + j;                                  \
        s16x4 pa = {su[0], su[1], su[2], su[3]};                         \
        s16x4 pb = {sn[0], sn[1], sn[2], sn[3]};                         \
        s16x4 pc = {sv[0], sv[1], sv[2], sv[3]};                         \
        *(s16x4*)&usp[smp2 * USTR + h4]       = pa;                      \
        *(s16x4*)&usp[smp2 * USTR + 128 + h4] = pb;                      \
        *(s16x4*)&sst[smp2 * SSTR + h4]       = pc;                      \
    }
    EWST(0)
    EWST(1)
#undef EWST

    __syncthreads();   // barrier 1: u/-sp/s staged by all h-tiles

    // ---- rhs GEMM (waves 0,1): rhs = [A^T|B^T].[u;-sp], K=256; D lands in solve layout ----
    f32x4 racc = {0.0f, 0.0f, 0.0f, 0.0f};
    if (wave < 2) {
#pragma unroll
        for (int kc = 0; kc < 8; ++kc) {
            bf16x8 af = *(const bf16x8*)&ABT[j * ASTR + (kc << 5) + (grp << 3)];
            bf16x8 bf = *(const bf16x8*)&usp[(wave * 16 + j) * USTR + (kc << 5) + (grp << 3)];
            racc = __builtin_amdgcn_mfma_f32_16x16x32_bf16(af, bf, racc, 0, 0, 0);
        }
    }

    // ---- M = I + B~^T diag(s) B~ via MFMA (v7-validated); wave's samples 4w..4w+3 ----
    f32x4 acc[4];
    {
        f32x4 ident;
#pragma unroll
        for (int r = 0; r < 4; ++r) ident[r] = ((grp << 2) + r == j) ? 1.0f : 0.0f;
#pragma unroll
        for (int gs = 0; gs < 4; ++gs) acc[gs] = ident;
    }
#pragma unroll
    for (int kc = 0; kc < 4; ++kc) {
        bf16x8 bfrag = *(const bf16x8*)&ABT[j * ASTR + 128 + (kc << 5) + (grp << 3)];
        float Bf[8];
#pragma unroll
        for (int e = 0; e < 8; ++e) Bf[e] = bf2f(bfrag[e]);
#pragma unroll
        for (int gs = 0; gs < 4; ++gs) {
            bf16x8 sfrag = *(const bf16x8*)&sst[(wave * 4 + gs) * SSTR + (kc << 5) + (grp << 3)];
            bf16x8 afrag;
#pragma unroll
            for (int e = 0; e < 8; ++e) afrag[e] = f2bf(bf2f(sfrag[e]) * Bf[e]);
            acc[gs] = __builtin_amdgcn_mfma_f32_16x16x32_bf16(afrag, bfrag, acc[gs], 0, 0, 0);
        }
    }

    __syncthreads();   // barrier 2: all GEMM reads of Wbf/Ybf/ABT/usp/sst done -> Mscr overlay

    float* Mscr = (float*)(smem + OFF_MSCR);
    // M symmetric: D(rows 4grp..4grp+3, col j) == M[j][4grp..4grp+3] -> one b128/sample.
#pragma unroll
    for (int gs = 0; gs < 4; ++gs) {
        float4 v;
        v.x = acc[gs][0]; v.y = acc[gs][1]; v.z = acc[gs][2]; v.w = acc[gs][3];
        *(float4*)&Mscr[mswz(wave * 4 + gs, j * 20 + (grp << 2))] = v;
    }

    __syncthreads();   // barrier 3: scratch complete

    // ---- solve (waves 0,1; 16 samples each; 4 lanes/sample, 4 rows/lane) ----
    if (wave >= 2) return;
    const int sl = lane & 15;            // sample within this wave's half
    const int rb = lane >> 4;            // row block (rows 4rb..4rb+3)
    const int s  = wave * 16 + sl;       // sample within block

    float M4[4][16], r4[4], d4[4];
#pragma unroll
    for (int r = 0; r < 4; ++r) {
        const int ro = (4 * rb + r) * 20;
        float4 v0 = *(const float4*)&Mscr[mswz(s, ro + 0)];
        float4 v1 = *(const float4*)&Mscr[mswz(s, ro + 4)];
        float4 v2 = *(const float4*)&Mscr[mswz(s, ro + 8)];
        float4 v3 = *(const float4*)&Mscr[mswz(s, ro + 12)];
        M4[r][0]=v0.x; M4[r][1]=v0.y; M4[r][2]=v0.z; M4[r][3]=v0.w;
        M4[r][4]=v1.x; M4[r][5]=v1.y; M4[r][6]=v1.z; M4[r][7]=v1.w;
        M4[r][8]=v2.x; M4[r][9]=v2.y; M4[r][10]=v2.z; M4[r][11]=v2.w;
        M4[r][12]=v3.x; M4[r][13]=v3.y; M4[r][14]=v3.z; M4[r][15]=v3.w;
        r4[r] = racc[r];                 // rhs already in the right lane/reg
        d4[r] = 1.0f;
    }

    // Gauss-Jordan, non-normalizing, triangular skip (v7-validated).
#pragma unroll
    for (int k = 0; k < 16; ++k) {
        const int src = sl + ((k >> 2) << 4);
        float piv = __shfl(M4[k & 3][k], src, 64);
        float rk  = __shfl(r4[k & 3], src, 64);
        float invp = __builtin_amdgcn_rcpf(piv);
        invp = invp * (2.0f - piv * invp);
        float f[4];
#pragma unroll
        for (int r = 0; r < 4; ++r) {
            float fr = M4[r][k] * invp;
            const bool isk = ((rb << 2) + r) == k;
            f[r]  = isk ? 0.0f : fr;
            d4[r] = isk ? piv : d4[r];
            r4[r] = fmaf(-f[r], rk, r4[r]);
        }
#pragma unroll
        for (int i = k + 1; i < 16; ++i) {
            float p = __shfl(M4[k & 3][i], src, 64);
            M4[0][i] = fmaf(-f[0], p, M4[0][i]);
            M4[1][i] = fmaf(-f[1], p, M4[1][i]);
            M4[2][i] = fmaf(-f[2], p, M4[2][i]);
            M4[3][i] = fmaf(-f[3], p, M4[3][i]);
        }
    }

    float4 xo;
    {
        float i0 = __builtin_amdgcn_rcpf(d4[0]); i0 = i0 * (2.0f - d4[0] * i0);
        float i1 = __builtin_amdgcn_rcpf(d4[1]); i1 = i1 * (2.0f - d4[1] * i1);
        float i2 = __builtin_amdgcn_rcpf(d4[2]); i2 = i2 * (2.0f - d4[2] * i2);
        float i3 = __builtin_amdgcn_rcpf(d4[3]); i3 = i3 * (2.0f - d4[3] * i3);
        xo.x = r4[0] * i0; xo.y = r4[1] * i1; xo.z = r4[2] * i2; xo.w = r4[3] * i3;
    }
    *(float4*)&out[(s0 + s) * DIMQ + (rb << 2)] = xo;
}

extern "C" void kernel_launch(void* const* d_in, const int* in_sizes, int n_in,
                              void* d_out, int out_size, void* d_ws, size_t ws_size,
                              hipStream_t stream) {
    const float* y  = (const float*)d_in[0];
    const float* W1 = (const float*)d_in[1];
    const float* b1 = (const float*)d_in[2];
    const float* w2 = (const float*)d_in[3];
    float* out = (float*)d_out;
    const int batch = in_sizes[0] / 32;          // 32768
    const int blocks = (batch + SPB - 1) / SPB;  // 1024
    lag_accel_kernel<<<blocks, NTHREADS, 0, stream>>>(y, W1, b1, w2, out);
}